// Round 1
// baseline (269.667 us; speedup 1.0000x reference)
//
#include <hip/hip_runtime.h>
#include <hip/hip_bf16.h>

// GraphAttention2: N=6144 nodes, F=128, C=64, H=4 heads, A ~1% sparse + self loops.
// out[n,c] = relu( mean_h( softmax_j(mask(leaky(att_s[h,n]+att_n[h,j]))) @ feats[h] + feats2[h] + bias[h] ) )
// Key: logits are rank-1 (no QK matmul) and masked entries underflow exp() to exactly 0,
// so sparse neighbor-only aggregation is numerically equivalent.

#define N_NODES 6144
#define F_DIM   128
#define C_DIM   64
#define H_HEADS 4
#define MAXK    512   // max neighbors per row; binomial(6143,0.01) max ~100, huge margin

// ---------------------------------------------------------------------------
// Kernel 1: per-head projections feats = X@W1[h], feats2 = X@W2[h], plus
// att_s/att_n (row dot a_self/a_neigh) fused into the epilogue for W1 blocks.
// Grid: (N/64, H*2). Block: 256 threads, 64x64 output tile, K=128 LDS-resident.
// ---------------------------------------------------------------------------
__global__ __launch_bounds__(256) void proj_kernel(
    const float* __restrict__ X,
    const float* __restrict__ W1, const float* __restrict__ W2,
    const float* __restrict__ a_self, const float* __restrict__ a_neigh,
    float* __restrict__ feats, float* __restrict__ feats2,
    float* __restrict__ att_s, float* __restrict__ att_n)
{
    const int rt    = blockIdx.x;       // row tile (64 rows)
    const int z     = blockIdx.y;       // 0..7
    const int h     = z >> 1;
    const int which = z & 1;            // 0 -> W1/feats, 1 -> W2/feats2

    const float* W   = (which ? W2 : W1) + h * F_DIM * C_DIM;
    float*       out = (which ? feats2 : feats) + (size_t)h * N_NODES * C_DIM;

    __shared__ float Xs[64][132];   // [r][k], pad 4 -> 2-way max conflict (free)
    __shared__ float Ws[128][68];   // [k][c], pad 4, float4-aligned rows

    const int tid = threadIdx.x;

    // Load X tile (64 rows x 128 cols) coalesced float4
    {
        const float4* Xg = (const float4*)(X + (size_t)rt * 64 * F_DIM);
        for (int u = tid; u < 64 * 32; u += 256) {
            const int r = u >> 5, q = u & 31;
            *(float4*)&Xs[r][4 * q] = Xg[u];
        }
        const float4* Wg = (const float4*)W;   // 128 rows x 16 float4
        for (int u = tid; u < 128 * 16; u += 256) {
            const int k = u >> 4, q = u & 15;
            *(float4*)&Ws[k][4 * q] = Wg[u];
        }
    }
    __syncthreads();

    const int tx = tid & 15;   // col group: cols 4*tx .. 4*tx+3
    const int ty = tid >> 4;   // row group: rows 4*ty .. 4*ty+3

    float acc[4][4] = {};
    #pragma unroll 4
    for (int k = 0; k < 128; ++k) {
        const float4 b = *(const float4*)&Ws[k][tx * 4];
        const float a0 = Xs[ty * 4 + 0][k];
        const float a1 = Xs[ty * 4 + 1][k];
        const float a2 = Xs[ty * 4 + 2][k];
        const float a3 = Xs[ty * 4 + 3][k];
        acc[0][0] += a0 * b.x; acc[0][1] += a0 * b.y; acc[0][2] += a0 * b.z; acc[0][3] += a0 * b.w;
        acc[1][0] += a1 * b.x; acc[1][1] += a1 * b.y; acc[1][2] += a1 * b.z; acc[1][3] += a1 * b.w;
        acc[2][0] += a2 * b.x; acc[2][1] += a2 * b.y; acc[2][2] += a2 * b.z; acc[2][3] += a2 * b.w;
        acc[3][0] += a3 * b.x; acc[3][1] += a3 * b.y; acc[3][2] += a3 * b.z; acc[3][3] += a3 * b.w;
    }

    __syncthreads();  // done reading Xs; safe to reuse as C-tile scratch
    float* Ct = &Xs[0][0];  // viewed as [64][65]

    #pragma unroll
    for (int i = 0; i < 4; ++i) {
        const int r = 4 * ty + i;
        float4 v = make_float4(acc[i][0], acc[i][1], acc[i][2], acc[i][3]);
        *(float4*)&out[(size_t)(rt * 64 + r) * C_DIM + 4 * tx] = v;
        if (which == 0) {
            Ct[r * 65 + 4 * tx + 0] = acc[i][0];
            Ct[r * 65 + 4 * tx + 1] = acc[i][1];
            Ct[r * 65 + 4 * tx + 2] = acc[i][2];
            Ct[r * 65 + 4 * tx + 3] = acc[i][3];
        }
    }

    if (which == 0) {
        __syncthreads();
        if (tid < 64) {
            const float* as_ = a_self  + h * C_DIM;
            const float* an_ = a_neigh + h * C_DIM;
            float s = 0.f, n = 0.f;
            #pragma unroll 8
            for (int c = 0; c < C_DIM; ++c) {
                const float v = Ct[tid * 65 + c];
                s += v * as_[c];
                n += v * an_[c];
            }
            att_s[h * N_NODES + rt * 64 + tid] = s;
            att_n[h * N_NODES + rt * 64 + tid] = n;
        }
    }
}

// ---------------------------------------------------------------------------
// Kernel 2: per-row sparse softmax-aggregation. One block per node row.
//   Phase A: scan A row (float4, coalesced), collect nonzero column indices.
//   Phase B: logits l = leaky(s_i + n_j); per-head max/sum (one wave per head).
//   Phase C: thread (h = tid>>6, c = tid&63) accumulates sum_k e[h][k]*feats[h,j_k,c]
//            (64-lane coalesced 256B gathers, feats is L2/LIC resident).
//   Phase D: mean over heads + relu, 64 threads write the output row.
// ---------------------------------------------------------------------------
__global__ __launch_bounds__(256) void agg_kernel(
    const float* __restrict__ A,
    const float* __restrict__ feats, const float* __restrict__ feats2,
    const float* __restrict__ att_s, const float* __restrict__ att_n,
    const float* __restrict__ bias,
    float* __restrict__ out)
{
    const int i   = blockIdx.x;
    const int tid = threadIdx.x;

    __shared__ int   idx[MAXK];
    __shared__ int   cnt;
    __shared__ float ew[H_HEADS][MAXK];
    __shared__ float mh[H_HEADS], Zh[H_HEADS], si[H_HEADS];
    __shared__ float nodebuf[256];

    if (tid == 0) cnt = 0;
    if (tid < H_HEADS) si[tid] = att_s[tid * N_NODES + i];
    __syncthreads();

    // Phase A: scan adjacency row
    const float4* Arow = (const float4*)(A + (size_t)i * N_NODES);
    for (int u = tid; u < N_NODES / 4; u += 256) {
        const float4 v = Arow[u];
        if (v.x > 0.5f) { int p = atomicAdd(&cnt, 1); if (p < MAXK) idx[p] = 4 * u + 0; }
        if (v.y > 0.5f) { int p = atomicAdd(&cnt, 1); if (p < MAXK) idx[p] = 4 * u + 1; }
        if (v.z > 0.5f) { int p = atomicAdd(&cnt, 1); if (p < MAXK) idx[p] = 4 * u + 2; }
        if (v.w > 0.5f) { int p = atomicAdd(&cnt, 1); if (p < MAXK) idx[p] = 4 * u + 3; }
    }
    __syncthreads();
    const int K = min(cnt, MAXK);

    // Phase B1: logits
    for (int k = tid; k < K; k += 256) {
        const int j = idx[k];
        #pragma unroll
        for (int h = 0; h < H_HEADS; ++h) {
            float l = si[h] + att_n[h * N_NODES + j];
            l = (l > 0.f) ? l : 0.2f * l;
            ew[h][k] = l;
        }
    }
    __syncthreads();

    const int w    = tid >> 6;   // wave id == head id
    const int lane = tid & 63;

    // Phase B2: per-head max (one wave per head)
    {
        float m = -1e30f;
        for (int k = lane; k < K; k += 64) m = fmaxf(m, ew[w][k]);
        #pragma unroll
        for (int off = 32; off > 0; off >>= 1) m = fmaxf(m, __shfl_down(m, off));
        if (lane == 0) mh[w] = m;
    }
    __syncthreads();

    // Phase B3: exp + per-head sum
    {
        const float m = mh[w];
        float zsum = 0.f;
        for (int k = lane; k < K; k += 64) {
            const float e = __expf(ew[w][k] - m);
            ew[w][k] = e;
            zsum += e;
        }
        #pragma unroll
        for (int off = 32; off > 0; off >>= 1) zsum += __shfl_down(zsum, off);
        if (lane == 0) Zh[w] = zsum;
    }
    __syncthreads();

    // Phase C: gather-accumulate. h = w, c = lane -> coalesced 256B loads per wave
    const int h = w, c = lane;
    const float* fh = feats + (size_t)h * N_NODES * C_DIM + c;
    float acc = 0.f;
    for (int k = 0; k < K; ++k) {
        acc += ew[h][k] * fh[(size_t)idx[k] * C_DIM];
    }
    const float node = acc / Zh[h]
                     + feats2[((size_t)h * N_NODES + i) * C_DIM + c]
                     + bias[h * C_DIM + c];
    nodebuf[tid] = node;
    __syncthreads();

    // Phase D: head mean + relu
    if (tid < 64) {
        const float s = nodebuf[tid] + nodebuf[64 + tid] + nodebuf[128 + tid] + nodebuf[192 + tid];
        out[(size_t)i * C_DIM + tid] = fmaxf(0.25f * s, 0.f);
    }
}

extern "C" void kernel_launch(void* const* d_in, const int* in_sizes, int n_in,
                              void* d_out, int out_size, void* d_ws, size_t ws_size,
                              hipStream_t stream) {
    const float* X       = (const float*)d_in[0];
    const float* A       = (const float*)d_in[1];
    const float* W1      = (const float*)d_in[2];
    const float* W2      = (const float*)d_in[3];
    const float* a_self  = (const float*)d_in[4];
    const float* a_neigh = (const float*)d_in[5];
    const float* bias    = (const float*)d_in[6];
    float* out = (float*)d_out;

    // Workspace layout (floats): feats | feats2 | att_s | att_n  (~12.8 MB)
    float* ws     = (float*)d_ws;
    float* feats  = ws;                                        // H*N*C
    float* feats2 = feats  + (size_t)H_HEADS * N_NODES * C_DIM;
    float* att_s  = feats2 + (size_t)H_HEADS * N_NODES * C_DIM;
    float* att_n  = att_s  + (size_t)H_HEADS * N_NODES;

    dim3 grid1(N_NODES / 64, H_HEADS * 2);
    proj_kernel<<<grid1, 256, 0, stream>>>(X, W1, W2, a_self, a_neigh,
                                           feats, feats2, att_s, att_n);

    agg_kernel<<<N_NODES, 256, 0, stream>>>(A, feats, feats2, att_s, att_n, bias, out);
}

// Round 3
// 266.254 us; speedup vs baseline: 1.0128x; 1.0128x over previous
//
#include <hip/hip_runtime.h>
#include <hip/hip_bf16.h>

// GraphAttention2: N=6144, F=128, C=64, H=4. A ~1% sparse + self loops.
// Sparse neighbor-only softmax-aggregation (masked exp underflows to exact 0).
// R2 (resubmitted after GPU acquisition timeout): 8-way batched gathers in
// phase C (MLP=8), fused layouts ([n][h][c] feats, [n][h] att vectors),
// k-vectorized proj inner loop.

#define N_NODES 6144
#define F_DIM   128
#define C_DIM   64
#define H_HEADS 4
#define HC      (H_HEADS * C_DIM)   // 256
#define MAXK    512   // max neighbors/row; E[K]=62, sigma~7.8 -> huge margin

// ---------------------------------------------------------------------------
// Kernel 1: per-head projections, outputs in fused layout:
//   featsT / feats2T : [N][H][C]   (1 KB per node)
//   attsT / attnT    : [N][H]      (16 B per node)
// Grid: (N/64, H*2). Block 256, 64x64 tile, K=128 LDS-resident.
// ---------------------------------------------------------------------------
__global__ __launch_bounds__(256) void proj_kernel(
    const float* __restrict__ X,
    const float* __restrict__ W1, const float* __restrict__ W2,
    const float* __restrict__ a_self, const float* __restrict__ a_neigh,
    float* __restrict__ featsT, float* __restrict__ feats2T,
    float* __restrict__ attsT, float* __restrict__ attnT)
{
    const int rt    = blockIdx.x;
    const int z     = blockIdx.y;
    const int h     = z >> 1;
    const int which = z & 1;

    const float* W    = (which ? W2 : W1) + h * F_DIM * C_DIM;
    float*       outp = which ? feats2T : featsT;

    __shared__ float  Xs[64][132];    // [r][k], +4 pad
    __shared__ float4 Ws4[128][17];   // [k][c/4], +1 float4 pad

    const int tid = threadIdx.x;

    {
        const float4* Xg = (const float4*)(X + (size_t)rt * 64 * F_DIM);
        for (int u = tid; u < 64 * 32; u += 256) {
            const int r = u >> 5, q = u & 31;
            *(float4*)&Xs[r][4 * q] = Xg[u];
        }
        const float4* Wg = (const float4*)W;
        for (int u = tid; u < 128 * 16; u += 256) {
            Ws4[u >> 4][u & 15] = Wg[u];
        }
    }
    __syncthreads();

    const int tx = tid & 15;   // cols 4*tx..4*tx+3
    const int ty = tid >> 4;   // rows 4*ty..4*ty+3

    float acc[4][4] = {};
    for (int k = 0; k < 128; k += 4) {
        const float4 b0 = Ws4[k + 0][tx];
        const float4 b1 = Ws4[k + 1][tx];
        const float4 b2 = Ws4[k + 2][tx];
        const float4 b3 = Ws4[k + 3][tx];
        #pragma unroll
        for (int i = 0; i < 4; ++i) {
            const float4 x = *(const float4*)&Xs[4 * ty + i][k];
            acc[i][0] += x.x * b0.x + x.y * b1.x + x.z * b2.x + x.w * b3.x;
            acc[i][1] += x.x * b0.y + x.y * b1.y + x.z * b2.y + x.w * b3.y;
            acc[i][2] += x.x * b0.z + x.y * b1.z + x.z * b2.z + x.w * b3.z;
            acc[i][3] += x.x * b0.w + x.y * b1.w + x.z * b2.w + x.w * b3.w;
        }
    }

    __syncthreads();           // Xs no longer needed; reuse as C-tile scratch
    float* Ct = &Xs[0][0];     // viewed as [64][65]

    #pragma unroll
    for (int i = 0; i < 4; ++i) {
        const int r    = 4 * ty + i;
        const int node = rt * 64 + r;
        *(float4*)&outp[(size_t)node * HC + h * C_DIM + 4 * tx] =
            make_float4(acc[i][0], acc[i][1], acc[i][2], acc[i][3]);
        if (which == 0) {
            Ct[r * 65 + 4 * tx + 0] = acc[i][0];
            Ct[r * 65 + 4 * tx + 1] = acc[i][1];
            Ct[r * 65 + 4 * tx + 2] = acc[i][2];
            Ct[r * 65 + 4 * tx + 3] = acc[i][3];
        }
    }

    if (which == 0) {
        __syncthreads();
        if (tid < 64) {
            const float* as_ = a_self  + h * C_DIM;
            const float* an_ = a_neigh + h * C_DIM;
            float s = 0.f, n = 0.f;
            #pragma unroll 8
            for (int c = 0; c < C_DIM; ++c) {
                const float v = Ct[tid * 65 + c];
                s += v * as_[c];
                n += v * an_[c];
            }
            const int node = rt * 64 + tid;
            attsT[node * H_HEADS + h] = s;
            attnT[node * H_HEADS + h] = n;
        }
    }
}

// ---------------------------------------------------------------------------
// Kernel 2: per-row sparse softmax-aggregation. One block (256) per node.
//   A: scan A row (float4) -> compact neighbor indices (LDS atomic counter).
//   B: logits via one float4 attnT load per neighbor; per-head max/exp/sum
//      (one wave per head, planar ews[4][MAXK] -> conflict-free).
//   C: 8-way batched gather: int4/float4 LDS chunk reads + 8 independent
//      global loads per chunk -> MLP=8 instead of 1.
//   D: epilogue: /Z + feats2 + bias, head mean, relu.
// ---------------------------------------------------------------------------
__global__ __launch_bounds__(256) void agg_kernel(
    const float* __restrict__ A,
    const float* __restrict__ featsT, const float* __restrict__ feats2T,
    const float* __restrict__ attsT, const float* __restrict__ attnT,
    const float* __restrict__ bias,
    float* __restrict__ out)
{
    const int i   = blockIdx.x;
    const int tid = threadIdx.x;

    __shared__ int   idx[MAXK];
    __shared__ float ews[H_HEADS][MAXK];
    __shared__ int   cnt;
    __shared__ float mh[H_HEADS], Zh[H_HEADS], si[H_HEADS];
    __shared__ float nodebuf[256];

    if (tid == 0) cnt = 0;
    if (tid < H_HEADS) si[tid] = attsT[i * H_HEADS + tid];
    __syncthreads();

    // Phase A: scan adjacency row, compact indices
    const float4* Arow = (const float4*)(A + (size_t)i * N_NODES);
    for (int u = tid; u < N_NODES / 4; u += 256) {
        const float4 v = Arow[u];
        if (v.x > 0.5f) { int p = atomicAdd(&cnt, 1); if (p < MAXK) idx[p] = 4 * u + 0; }
        if (v.y > 0.5f) { int p = atomicAdd(&cnt, 1); if (p < MAXK) idx[p] = 4 * u + 1; }
        if (v.z > 0.5f) { int p = atomicAdd(&cnt, 1); if (p < MAXK) idx[p] = 4 * u + 2; }
        if (v.w > 0.5f) { int p = atomicAdd(&cnt, 1); if (p < MAXK) idx[p] = 4 * u + 3; }
    }
    __syncthreads();
    const int K = min(cnt, MAXK);

    // Phase B1: logits (one float4 load gives all 4 heads)
    const float4* an4 = (const float4*)attnT;
    for (int k = tid; k < K; k += 256) {
        const float4 an = an4[idx[k]];
        float l;
        l = si[0] + an.x; ews[0][k] = (l > 0.f) ? l : 0.2f * l;
        l = si[1] + an.y; ews[1][k] = (l > 0.f) ? l : 0.2f * l;
        l = si[2] + an.z; ews[2][k] = (l > 0.f) ? l : 0.2f * l;
        l = si[3] + an.w; ews[3][k] = (l > 0.f) ? l : 0.2f * l;
    }
    __syncthreads();

    const int w    = tid >> 6;   // wave id == head id
    const int lane = tid & 63;

    // Phase B2: per-head max
    {
        float m = -1e30f;
        for (int k = lane; k < K; k += 64) m = fmaxf(m, ews[w][k]);
        #pragma unroll
        for (int off = 32; off > 0; off >>= 1) m = fmaxf(m, __shfl_down(m, off));
        if (lane == 0) mh[w] = m;
    }
    __syncthreads();

    // Phase B3: exp + per-head sum
    {
        const float m = mh[w];
        float zsum = 0.f;
        for (int k = lane; k < K; k += 64) {
            const float e = __expf(ews[w][k] - m);
            ews[w][k] = e;
            zsum += e;
        }
        #pragma unroll
        for (int off = 32; off > 0; off >>= 1) zsum += __shfl_down(zsum, off);
        if (lane == 0) Zh[w] = zsum;
    }
    __syncthreads();

    // Phase C: batched gather-accumulate, 8 loads in flight per chunk
    const int h = w, c = lane;
    const float* fh = featsT + h * C_DIM + c;   // stride HC=256 per node
    float acc = 0.f;
    int k = 0;
    for (; k + 8 <= K; k += 8) {
        const int4   j0 = *(const int4*)&idx[k];
        const int4   j1 = *(const int4*)&idx[k + 4];
        const float4 w0 = *(const float4*)&ews[h][k];
        const float4 w1 = *(const float4*)&ews[h][k + 4];
        const float f0 = fh[(size_t)j0.x * HC];
        const float f1 = fh[(size_t)j0.y * HC];
        const float f2 = fh[(size_t)j0.z * HC];
        const float f3 = fh[(size_t)j0.w * HC];
        const float f4 = fh[(size_t)j1.x * HC];
        const float f5 = fh[(size_t)j1.y * HC];
        const float f6 = fh[(size_t)j1.z * HC];
        const float f7 = fh[(size_t)j1.w * HC];
        acc += w0.x * f0 + w0.y * f1 + w0.z * f2 + w0.w * f3
             + w1.x * f4 + w1.y * f5 + w1.z * f6 + w1.w * f7;
    }
    for (; k < K; ++k) acc += ews[h][k] * fh[(size_t)idx[k] * HC];

    const float node = acc / Zh[h]
                     + feats2T[(size_t)i * HC + tid]
                     + bias[tid];                 // bias[h][c] == bias[tid]
    nodebuf[tid] = node;
    __syncthreads();

    // Phase D: head mean + relu
    if (tid < 64) {
        const float s = nodebuf[tid] + nodebuf[64 + tid] + nodebuf[128 + tid] + nodebuf[192 + tid];
        out[(size_t)i * C_DIM + tid] = fmaxf(0.25f * s, 0.f);
    }
}

extern "C" void kernel_launch(void* const* d_in, const int* in_sizes, int n_in,
                              void* d_out, int out_size, void* d_ws, size_t ws_size,
                              hipStream_t stream) {
    const float* X       = (const float*)d_in[0];
    const float* A       = (const float*)d_in[1];
    const float* W1      = (const float*)d_in[2];
    const float* W2      = (const float*)d_in[3];
    const float* a_self  = (const float*)d_in[4];
    const float* a_neigh = (const float*)d_in[5];
    const float* bias    = (const float*)d_in[6];
    float* out = (float*)d_out;

    // Workspace layout (floats): featsT | feats2T | attsT | attnT (~12.8 MB)
    float* ws      = (float*)d_ws;
    float* featsT  = ws;                                    // N*H*C
    float* feats2T = featsT  + (size_t)N_NODES * HC;
    float* attsT   = feats2T + (size_t)N_NODES * HC;        // N*H
    float* attnT   = attsT   + (size_t)N_NODES * H_HEADS;

    dim3 grid1(N_NODES / 64, H_HEADS * 2);
    proj_kernel<<<grid1, 256, 0, stream>>>(X, W1, W2, a_self, a_neigh,
                                           featsT, feats2T, attsT, attnT);

    agg_kernel<<<N_NODES, 256, 0, stream>>>(A, featsT, feats2T, attsT, attnT, bias, out);
}